// Round 15
// baseline (311.387 us; speedup 1.0000x reference)
//
#include <hip/hip_runtime.h>
#include <hip/hip_bf16.h>
#include <hip/hip_fp16.h>

// Problem constants (from reference)
#define NP   3        // metapaths
#define NE   250000   // edges per metapath
#define NL   3        // metapath length
#define NT   8192     // targets
#define NN   100000   // nodes
#define IND  64       // in_dim
#define ND2  32       // in_dim/2 complex pairs
#define NH   8        // heads
#define NAD  128      // attn_vec_dim
#define NOD  64       // out_dim
#define NHD  512      // heads * in_dim
#define LALPHA 0.01f
#define NSEG (NP*NT)
#define NB   16       // nodes per block in k_final

typedef __attribute__((ext_vector_type(8))) _Float16 half8;
typedef __attribute__((ext_vector_type(4))) _Float16 half4;
typedef __attribute__((ext_vector_type(4))) float f32x4;
typedef __attribute__((ext_vector_type(4))) unsigned int uint4v;

// ---------------- NEW-path ws layout (words). NEED = 25872000 words ---------
#define FLAG_W    0
#define FINALR_W  64        // 576
#define ATILDE_W  704       // 4608 : atilde [p][l][h][64] f32 (1/3 folded in)
#define BETAACC_N 5376      // 384
#define BETA_N    5760      // 4
#define COUNTS_N  6144      // 24576
#define OFFS_N    30720     // 24577
#define CURSOR_N  55360     // 24576
#define EIDX_N    80000     // 3000000 (750000 int4; BYTE-scaled node offsets)
#define ATTNF_N   3080000   // 1536
#define FC1W_N    3081600   // slot: fc1_w staged f16 [128][512]
#define FC1B_N    3147136   // 128
#define FC2W_N    3147264   // 128
#define FCW_N     3147392   // slot: fc_w staged f16 [64][512]
#define FCB_N     3180160   // 64
#define RVEC_N    3180224   // 192
#define FEATH_N   3180544   // 3200000 words = 6.4M f16
#define SCORE_N   6380544   // 7200000 : S [NN][72]  (c*8+h within row)
#define OUTS_N    13580544  // 6291456 words = 12.58M f16 : elu(outs) [P][NT][512]
#define EH_N      19872000  // 6000000 f32 : EH[pos][8] = exp(leaky(score))
#define NEED_WORDS 25872000UL   // <= 26163456 proven present since round 4

// ---------------- FALLBACK ws layout (round-3 proven; outs f16) -------------
#define BETAACC_F 1024
#define BETA_F    1472
#define COUNTS_F  2048
#define OFFS_F    26624
#define CURSOR_F  51264
#define ELIST_F   75904
#define FEATF_F   825920
#define ATTNF_F   7225920
#define FC1W_F    7227456
#define FC1B_F    7292992
#define FC2W_F    7293120
#define FCW_F     7293248
#define FCB_F     7326016
#define RVEC_F    7326080
#define OUTS_F    7326272

__device__ __forceinline__ float bf2f(unsigned short u) {
    union { unsigned int i; float f; } c; c.i = ((unsigned int)u) << 16; return c.f;
}

// v_fma_mix_f32: acc = f32(f16 lo/hi of xpair) * s + acc  (cvt fused into fma)
__device__ __forceinline__ void fmamix_lo(float& acc, unsigned int xpair, float s) {
    asm("v_fma_mix_f32 %0, %1, %2, %0 op_sel_hi:[1,0,0]"
        : "+v"(acc) : "v"(xpair), "v"(s));
}
__device__ __forceinline__ void fmamix_hi(float& acc, unsigned int xpair, float s) {
    asm("v_fma_mix_f32 %0, %1, %2, %0 op_sel:[1,0,0] op_sel_hi:[1,0,0]"
        : "+v"(acc) : "v"(xpair), "v"(s));
}

// ---------------- k_prep: detect dtype + small cvts + finalr + atilde -------
__global__ __launch_bounds__(256) void k_prep(
        const unsigned short* __restrict__ feat_raw,
        const void* __restrict__ rvec_src, const void* __restrict__ attn_src,
        const void* __restrict__ fc1b_src, const void* __restrict__ fc2w_src,
        const void* __restrict__ fcb_src,
        float* __restrict__ ws, int* __restrict__ flag,
        float* __restrict__ rvecf, float* __restrict__ attnf,
        float* __restrict__ fc1bf, float* __restrict__ fc2wf,
        float* __restrict__ fcbf) {
    __shared__ int cnt;
    int t = threadIdx.x;
    if (t == 0) cnt = 0;
    __syncthreads();
    int wild = 0;
    for (int i = t; i < 512; i += 256) {
        unsigned short u = feat_raw[i];
        int e = (u >> 7) & 0xFF;
        if (u != 0 && (e < 0x60 || e > 0x90)) wild++;
    }
    for (int off = 32; off; off >>= 1) wild += __shfl_xor(wild, off);
    if ((t & 63) == 0) atomicAdd(&cnt, wild);
    __syncthreads();
    int f = cnt > 64 ? 1 : 0;
    if (t == 0) *flag = f;
    // small converts
    for (int i = t; i < 192; i += 256)
        rvecf[i] = f ? ((const float*)rvec_src)[i] : bf2f(((const unsigned short*)rvec_src)[i]);
    for (int i = t; i < 1536; i += 256)
        attnf[i] = f ? ((const float*)attn_src)[i] : bf2f(((const unsigned short*)attn_src)[i]);
    if (t < 128) fc1bf[t] = f ? ((const float*)fc1b_src)[t] : bf2f(((const unsigned short*)fc1b_src)[t]);
    if (t < 128) fc2wf[t] = f ? ((const float*)fc2w_src)[t] : bf2f(((const unsigned short*)fc2w_src)[t]);
    if (t < 64)  fcbf[t]  = f ? ((const float*)fcb_src)[t]  : bf2f(((const unsigned short*)fcb_src)[t]);
    __syncthreads();
    // finalr
    if (t < NP * ND2) {
        int p = t / ND2, j = t % ND2;
        float re = rvecf[(p * ND2 + j) * 2 + 0];
        float im = rvecf[(p * ND2 + j) * 2 + 1];
        float inv = rsqrtf(re * re + im * im);
        float nre = re * inv, nim = im * inv;
        float f1r = nre, f1i = -nim;              // f[1] = conj(r)
        float f0r = f1r * nre - f1i * nim;        // f[0] = f[1]*r
        float f0i = f1r * nim + f1i * nre;
        float* fr = ws + FINALR_W + p * NL * ND2 * 2;
        fr[(0 * ND2 + j) * 2 + 0] = f0r; fr[(0 * ND2 + j) * 2 + 1] = f0i;
        fr[(1 * ND2 + j) * 2 + 0] = f1r; fr[(1 * ND2 + j) * 2 + 1] = f1i;
        fr[(2 * ND2 + j) * 2 + 0] = 1.f; fr[(2 * ND2 + j) * 2 + 1] = 0.f;
    }
    __syncthreads();
    // atilde[p][l][h][d] = (1/3) * cmul(at[p,h], conj(c_pl))[d]
    const float* finalr = ws + FINALR_W;
    float* atil = ws + ATILDE_W;
    for (int i = t; i < NP * NL * NH * IND; i += 256) {
        int d = i & 63, h = (i >> 6) & 7, l = (i >> 9) % 3, p = i / (64 * 8 * 3);
        int j = d >> 1; bool im = (d & 1) != 0;
        float cr = finalr[(p * NL * ND2 + l * ND2 + j) * 2 + 0];
        float ci = finalr[(p * NL * ND2 + l * ND2 + j) * 2 + 1];
        float ar = attnf[(p * NH + h) * IND + 2 * j];
        float ai = attnf[(p * NH + h) * IND + 2 * j + 1];
        float v = im ? (ai * cr - ar * ci) : (ar * cr + ai * ci);
        atil[i] = v * (1.f / 3.f);
    }
}

// ---------------- generic converts -----------------------------------------
__global__ void k_cvt(const void* __restrict__ src, float* __restrict__ dst, int n,
                      const int* __restrict__ flag) {
    int i = blockIdx.x * blockDim.x + threadIdx.x;
    if (i >= n) return;
    if (*flag) dst[i] = ((const float*)src)[i];
    else       dst[i] = bf2f(((const unsigned short*)src)[i]);
}

__device__ __forceinline__ half4 cvt_one_h4(const void* src, int i, int f) {
    half4 o;
    if (f) {
        float4 v = ((const float4*)src)[i];
        o[0] = (_Float16)v.x; o[1] = (_Float16)v.y; o[2] = (_Float16)v.z; o[3] = (_Float16)v.w;
    } else {
        ushort4 u = ((const ushort4*)src)[i];
        o[0] = (_Float16)bf2f(u.x); o[1] = (_Float16)bf2f(u.y);
        o[2] = (_Float16)bf2f(u.z); o[3] = (_Float16)bf2f(u.w);
    }
    return o;
}

// dual f16 convert: fc1_w then fc_w in a single launch
__global__ void k_cvt_h4_dual(const void* __restrict__ s1, half4* __restrict__ d1, int n1,
                              const void* __restrict__ s2, half4* __restrict__ d2, int n2,
                              const int* __restrict__ flag) {
    int i = blockIdx.x * blockDim.x + threadIdx.x;
    int f = *flag;
    if (i < n1)            d1[i] = cvt_one_h4(s1, i, f);
    else if (i - n1 < n2)  d2[i - n1] = cvt_one_h4(s2, i - n1, f);
}

// ---------------- per-node scores (FUSED feature cvt): reads raw features,
// writes featH f16 AND S[n][c*8+h] (row stride 72) ---------------------------
__global__ __launch_bounds__(256) void k_score(const void* __restrict__ feat_src,
                                               const int* __restrict__ flag,
                                               const float* __restrict__ atil,
                                               float* __restrict__ S,
                                               _Float16* __restrict__ featH) {
    __shared__ float xs[128][68];
    __shared__ float as[72][68];
    int t = threadIdx.x;
    int nbase = blockIdx.x * 128;
    int f = *flag;
    for (int i = t; i < 72 * 64; i += 256) as[i >> 6][i & 63] = atil[i];
    for (int c = t; c < 2048; c += 256) {
        int nloc = c >> 4, cc = c & 15;
        int node = nbase + nloc;
        float4 v;
        if (node < NN) {
            if (f) v = ((const float4*)feat_src)[(size_t)node * 16 + cc];
            else {
                ushort4 u = ((const ushort4*)feat_src)[(size_t)node * 16 + cc];
                v = make_float4(bf2f(u.x), bf2f(u.y), bf2f(u.z), bf2f(u.w));
            }
        } else v = make_float4(0.f, 0.f, 0.f, 0.f);
        int d0 = cc * 4;
        xs[nloc][d0 + 0] = v.x; xs[nloc][d0 + 1] = v.y;
        xs[nloc][d0 + 2] = v.z; xs[nloc][d0 + 3] = v.w;
        if (node < NN) {
            half4 hv;
            hv[0] = (_Float16)v.x; hv[1] = (_Float16)v.y;
            hv[2] = (_Float16)v.z; hv[3] = (_Float16)v.w;
            *(half4*)(featH + (size_t)node * IND + d0) = hv;
        }
    }
    __syncthreads();
    int lane = t & 63, w = t >> 6;
    int g = lane >> 3, h = lane & 7;
    int nloc = (w * 8 + g) * 4;                      // 4 nodes per thread
    float acc[9][4];
#pragma unroll
    for (int c = 0; c < 9; c++)
#pragma unroll
        for (int u = 0; u < 4; u++) acc[c][u] = 0.f;
    for (int ch = 0; ch < 16; ch++) {
        float4 xv[4];
#pragma unroll
        for (int u = 0; u < 4; u++) xv[u] = *(const float4*)&xs[nloc + u][ch * 4];
#pragma unroll
        for (int c = 0; c < 9; c++) {
            float4 av = *(const float4*)&as[c * 8 + h][ch * 4];
#pragma unroll
            for (int u = 0; u < 4; u++)
                acc[c][u] += xv[u].x * av.x + xv[u].y * av.y + xv[u].z * av.z + xv[u].w * av.w;
        }
    }
#pragma unroll
    for (int u = 0; u < 4; u++) {
        int node = nbase + nloc + u;
        if (node < NN) {
#pragma unroll
            for (int c = 0; c < 9; c++)
                S[(long)node * 72 + c * 8 + h] = acc[c][u];
        }
    }
}

// ---------------- CSR build -------------------------------------------------
__global__ void k_count(const int* __restrict__ dst, int* __restrict__ counts) {
    int id = blockIdx.x * blockDim.x + threadIdx.x;
    if (id >= NP * NE) return;
    int p = id / NE;
    atomicAdd(&counts[p * NT + dst[id]], 1);
}

__global__ __launch_bounds__(256) void k_scan(const int* __restrict__ counts,
                                              int* __restrict__ offs,
                                              int* __restrict__ cursor) {
    __shared__ int wtot[4];
    int t = threadIdx.x;
    const int CH = NSEG / 256;  // 96
    int base = t * CH;
    int s = 0;
    for (int i = 0; i < CH; i++) s += counts[base + i];
    int l = t & 63, w = t >> 6;
    int v = s;
    for (int off = 1; off < 64; off <<= 1) {
        int u = __shfl_up(v, off);
        if (l >= off) v += u;
    }
    if (l == 63) wtot[w] = v;
    __syncthreads();
    int wb = 0;
    for (int i = 0; i < w; i++) wb += wtot[i];
    int run = wb + v - s;
    for (int i = 0; i < CH; i++) {
        int c = counts[base + i];
        offs[base + i] = run; cursor[base + i] = run;
        run += c;
    }
    if (t == 255) offs[NSEG] = wb + v;
}

// scatter BYTE-scaled node triples AND compute EH[pos][h]
__global__ void k_scatter2(const int* __restrict__ dst, const int* __restrict__ indices,
                           int* __restrict__ cursor, int4* __restrict__ eidx,
                           const float* __restrict__ S, float* __restrict__ EH) {
    int id = blockIdx.x * blockDim.x + threadIdx.x;
    if (id >= NP * NE) return;
    int p = id / NE, e = id % NE;
    int pos = atomicAdd(&cursor[p * NT + dst[id]], 1);
    const int* ip = indices + (long)p * NE * NL + (long)e * NL;
    int n0 = ip[0], n1 = ip[1], n2 = ip[2];
    eidx[pos] = make_int4(n0 << 7, n1 << 7, n2 << 7, 0);   // bytes into featH
    const float* S0 = S + (long)n0 * 72 + p * 24;
    const float* S1 = S + (long)n1 * 72 + p * 24 + 8;
    const float* S2 = S + (long)n2 * 72 + p * 24 + 16;
    float4 a0 = *(const float4*)S0, b0 = *(const float4*)(S0 + 4);
    float4 a1 = *(const float4*)S1, b1 = *(const float4*)(S1 + 4);
    float4 a2 = *(const float4*)S2, b2 = *(const float4*)(S2 + 4);
    float4 lo, hi;
    {
        float s;
        s = a0.x + a1.x + a2.x; lo.x = __expf(fmaxf(s, LALPHA * s));
        s = a0.y + a1.y + a2.y; lo.y = __expf(fmaxf(s, LALPHA * s));
        s = a0.z + a1.z + a2.z; lo.z = __expf(fmaxf(s, LALPHA * s));
        s = a0.w + a1.w + a2.w; lo.w = __expf(fmaxf(s, LALPHA * s));
        s = b0.x + b1.x + b2.x; hi.x = __expf(fmaxf(s, LALPHA * s));
        s = b0.y + b1.y + b2.y; hi.y = __expf(fmaxf(s, LALPHA * s));
        s = b0.z + b1.z + b2.z; hi.z = __expf(fmaxf(s, LALPHA * s));
        s = b0.w + b1.w + b2.w; hi.w = __expf(fmaxf(s, LALPHA * s));
    }
    float* ehp = EH + (long)pos * 8;
    *(float4*)ehp = lo;
    *(float4*)(ehp + 4) = hi;
}

// fallback: scatter edge id only
__global__ void k_scatter(const int* __restrict__ dst, int* __restrict__ cursor,
                          int* __restrict__ elist) {
    int id = blockIdx.x * blockDim.x + threadIdx.x;
    if (id >= NP * NE) return;
    int p = id / NE, e = id % NE;
    int pos = atomicAdd(&cursor[p * NT + dst[id]], 1);
    elist[pos] = e;
}

// ---------------- edge aggregation: saddr voffsets; fma_mix; 2-stage pipe ---
// lane = 8*h + q handles (head h, dims d in [8q, 8q+8))
__global__ __launch_bounds__(64) void k_agg2(
        const _Float16* __restrict__ featH, const int4* __restrict__ eidx,
        const float* __restrict__ EH, const float* __restrict__ finalr,
        const int* __restrict__ offs, _Float16* __restrict__ outs) {
    int b = blockIdx.x;
    int p = b / NT;
    int t = threadIdx.x;
    int h = t >> 3, q = t & 7;
    const unsigned fB = (unsigned)(q << 4);   // q*8 elems * 2B
    const char* Fb = (const char*)featH;

    float a0[8], a1[8], a2[8];
#pragma unroll
    for (int r = 0; r < 8; r++) { a0[r] = 0.f; a1[r] = 0.f; a2[r] = 0.f; }
    float se = 0.f;

    int beg = offs[b], end = offs[b + 1];
    const float* EHh = EH + h;   // EH[pos*8 + h]

    int mend = beg + ((end - beg) & ~3);
    int i = beg;
    int4 ee[4]; float ehv[4];
    if (i < mend) {
#pragma unroll
        for (int u = 0; u < 4; u++) { ee[u] = eidx[i + u]; ehv[u] = EHh[(long)(i + u) * 8]; }
    }
    while (i < mend) {
        // issue x loads for the current group
        half8 x0[4], x1[4], x2[4];
#pragma unroll
        for (int u = 0; u < 4; u++) {
            x0[u] = *(const half8*)(Fb + (unsigned)((unsigned)ee[u].x + fB));
            x1[u] = *(const half8*)(Fb + (unsigned)((unsigned)ee[u].y + fB));
            x2[u] = *(const half8*)(Fb + (unsigned)((unsigned)ee[u].z + fB));
        }
        // prefetch next group's indices/weights (hidden under the FMA block)
        int inext = i + 4;
        int4 ee2[4]; float eh2[4];
        if (inext < mend) {
#pragma unroll
            for (int u = 0; u < 4; u++) {
                ee2[u] = eidx[inext + u];
                eh2[u] = EHh[(long)(inext + u) * 8];
            }
        }
        // compute
#pragma unroll
        for (int u = 0; u < 4; u++) {
            float eh = ehv[u];
            se += eh;
            uint4v w0 = __builtin_bit_cast(uint4v, x0[u]);
            uint4v w1 = __builtin_bit_cast(uint4v, x1[u]);
            uint4v w2 = __builtin_bit_cast(uint4v, x2[u]);
#pragma unroll
            for (int jp = 0; jp < 4; jp++) {
                fmamix_lo(a0[2 * jp], w0[jp], eh); fmamix_hi(a0[2 * jp + 1], w0[jp], eh);
                fmamix_lo(a1[2 * jp], w1[jp], eh); fmamix_hi(a1[2 * jp + 1], w1[jp], eh);
                fmamix_lo(a2[2 * jp], w2[jp], eh); fmamix_hi(a2[2 * jp + 1], w2[jp], eh);
            }
        }
#pragma unroll
        for (int u = 0; u < 4; u++) { ee[u] = ee2[u]; ehv[u] = eh2[u]; }
        i = inext;
    }
    for (; i < end; i++) {
        int4 e = eidx[i];
        float eh = EHh[(long)i * 8];
        se += eh;
        half8 x0 = *(const half8*)(Fb + (unsigned)((unsigned)e.x + fB));
        half8 x1 = *(const half8*)(Fb + (unsigned)((unsigned)e.y + fB));
        half8 x2 = *(const half8*)(Fb + (unsigned)((unsigned)e.z + fB));
#pragma unroll
        for (int r = 0; r < 8; r++) {
            a0[r] += eh * (float)x0[r];
            a1[r] += eh * (float)x1[r];
            a2[r] += eh * (float)x2[r];
        }
    }

    // epilogue: ft = (1/3) * sum_l rot_l(acc_l) / se ; elu ; f16 store
    const float* fr = finalr + p * NL * ND2 * 2;
    float sc = (end > beg) ? (1.f / 3.f) / se : 0.f;
    half8 o;
#pragma unroll
    for (int jj = 0; jj < 4; jj++) {
        int j = 4 * q + jj;
        float c0r = fr[(0 * ND2 + j) * 2 + 0], c0i = fr[(0 * ND2 + j) * 2 + 1];
        float c1r = fr[(1 * ND2 + j) * 2 + 0], c1i = fr[(1 * ND2 + j) * 2 + 1];
        float ar, ai, vr, vi;
        ar = a0[2 * jj]; ai = a0[2 * jj + 1];
        vr = ar * c0r - ai * c0i; vi = ar * c0i + ai * c0r;
        ar = a1[2 * jj]; ai = a1[2 * jj + 1];
        vr += ar * c1r - ai * c1i; vi += ar * c1i + ai * c1r;
        vr += a2[2 * jj]; vi += a2[2 * jj + 1];   // l=2 rotation is identity
        vr *= sc; vi *= sc;
        vr = vr > 0.f ? vr : __expf(vr) - 1.f;
        vi = vi > 0.f ? vi : __expf(vi) - 1.f;
        o[2 * jj]     = (_Float16)vr;
        o[2 * jj + 1] = (_Float16)vi;
    }
    *(half8*)(outs + (long)b * NHD + (h << 6) + (q << 3)) = o;
}

// ---------------- FALLBACK edge aggregation (round-3 proven; f16 store) -----
__global__ __launch_bounds__(64) void k_agg(
        const float* __restrict__ feat, const int* __restrict__ indices,
        const float* __restrict__ attn, const float* __restrict__ ws_f,
        const int* __restrict__ offs, const int* __restrict__ elist,
        _Float16* __restrict__ outs) {
    int b = blockIdx.x;
    int p = b / NT;
    int d = threadIdx.x;
    int j = d >> 1;
    bool isim = (d & 1) != 0;
    const float* fr = ws_f + FINALR_W + p * NL * ND2 * 2;
    float cr[NL], ci[NL];
#pragma unroll
    for (int l = 0; l < NL; l++) {
        cr[l] = fr[(l * ND2 + j) * 2 + 0];
        ci[l] = fr[(l * ND2 + j) * 2 + 1];
    }
    float at[NH];
#pragma unroll
    for (int h = 0; h < NH; h++) at[h] = attn[(p * NH + h) * IND + d];
    float ft[NH], se[NH];
#pragma unroll
    for (int h = 0; h < NH; h++) { ft[h] = 0.f; se[h] = 0.f; }
    int beg = offs[b], end = offs[b + 1];
    const int* idxp = indices + (long)p * NE * NL;
    for (int i = beg; i < end; i++) {
        int e = elist[i];
        int nn[3] = { idxp[e * 3 + 0], idxp[e * 3 + 1], idxp[e * 3 + 2] };
        float hid = 0.f;
#pragma unroll
        for (int l = 0; l < NL; l++) {
            float x = feat[(long)nn[l] * IND + d];
            float xp = __shfl_xor(x, 1);
            float re = isim ? xp : x;
            float im = isim ? x : xp;
            hid += isim ? (re * ci[l] + im * cr[l]) : (re * cr[l] - im * ci[l]);
        }
        hid *= (1.f / 3.f);
#pragma unroll
        for (int h = 0; h < NH; h++) {
            float v = hid * at[h];
#pragma unroll
            for (int off = 32; off; off >>= 1) v += __shfl_xor(v, off);
            float a = v > 0.f ? v : LALPHA * v;
            float eh = __expf(a);
            se[h] += eh;
            ft[h] += eh * hid;
        }
    }
    _Float16* orow = outs + (long)b * NHD;
    bool has = end > beg;
#pragma unroll
    for (int h = 0; h < NH; h++) {
        float v = has ? ft[h] / fmaxf(se[h], 1e-20f) : 0.f;
        v = v > 0.f ? v : (__expf(v) - 1.f);
        orow[h * IND + d] = (_Float16)v;
    }
}

// ---------------- fc1 -> tanh -> sum over nodes, via MFMA (round-9 proven) --
__global__ __launch_bounds__(256) void k_fc1(
        const _Float16* __restrict__ outs, const _Float16* __restrict__ fc1h,
        const float* __restrict__ fc1_b, float* __restrict__ betaacc) {
    __shared__ float red[4][NAD];
    int tid = threadIdx.x;
    int wid = tid >> 6, lane = tid & 63;
    int nt = blockIdx.x * 4 + wid;     // node-tile index (16 outs rows each)
    int p  = blockIdx.x / (NT / 16 / 4);  // 128 blocks per metapath
    int col = lane & 15, kq = lane >> 4;

    const _Float16* brow  = outs + ((long)nt * 16 + col) * NHD + kq * 8;
    const _Float16* abase = fc1h + (long)col * NHD + kq * 8;

    f32x4 acc[8];
#pragma unroll
    for (int ta = 0; ta < 8; ta++) acc[ta] = (f32x4){0.f, 0.f, 0.f, 0.f};

    for (int kk = 0; kk < 16; kk++) {
        half8 b = *(const half8*)(brow + kk * 32);
#pragma unroll
        for (int ta = 0; ta < 8; ta++) {
            half8 a = *(const half8*)(abase + (long)ta * 16 * NHD + kk * 32);
            acc[ta] = __builtin_amdgcn_mfma_f32_16x16x32_f16(a, b, acc[ta], 0, 0, 0);
        }
    }

#pragma unroll
    for (int ta = 0; ta < 8; ta++) {
#pragma unroll
        for (int r = 0; r < 4; r++) {
            int arow = ta * 16 + kq * 4 + r;
            float v = tanhf(acc[ta][r] + fc1_b[arow]);
            v += __shfl_xor(v, 1); v += __shfl_xor(v, 2);
            v += __shfl_xor(v, 4); v += __shfl_xor(v, 8);
            if (col == 0) red[wid][arow] = v;
        }
    }
    __syncthreads();
    if (tid < NAD) {
        float s = red[0][tid] + red[1][tid] + red[2][tid] + red[3][tid];
        atomicAdd(&betaacc[p * NAD + tid], s);
    }
}

__global__ void k_beta(const float* __restrict__ betaacc,
                       const float* __restrict__ fc2_w, float* __restrict__ beta) {
    __shared__ float lds[NP][NAD];
    int t = threadIdx.x;
    for (int p = 0; p < NP; p++)
        lds[p][t] = betaacc[p * NAD + t] * (1.f / NT) * fc2_w[t];
    __syncthreads();
    if (t == 0) {
        float s[NP];
        for (int p = 0; p < NP; p++) {
            s[p] = 0.f;
            for (int a = 0; a < NAD; a++) s[p] += lds[p][a];
        }
        float m = fmaxf(s[0], fmaxf(s[1], s[2]));
        float e0 = expf(s[0] - m), e1 = expf(s[1] - m), e2 = expf(s[2] - m);
        float inv = 1.f / (e0 + e1 + e2);
        beta[0] = e0 * inv; beta[1] = e1 * inv; beta[2] = e2 * inv;
    }
}

// ---------------- h = sum_p beta_p*outs_p ; h_fc via MFMA -------------------
__global__ __launch_bounds__(256) void k_final(
        const _Float16* __restrict__ outs, const float* __restrict__ beta,
        const _Float16* __restrict__ fcw16, const float* __restrict__ fc_b,
        void* __restrict__ outp, const int* __restrict__ flag) {
    __shared__ _Float16 h16[16][520];   // pad 520: uniform bank spread
    int n0 = blockIdx.x * NB;
    int t = threadIdx.x;
    int f = *flag;
    float b0 = beta[0], b1 = beta[1], b2 = beta[2];
    const _Float16* o0 = outs + (long)n0 * NHD;
    for (int c = t; c < NB * NHD / 8; c += 256) {
        int row = c >> 6, k0 = (c & 63) * 8;
        half8 v0 = *(const half8*)(o0 + row * NHD + k0);
        half8 v1 = *(const half8*)(o0 + (long)NT * NHD + row * NHD + k0);
        half8 v2 = *(const half8*)(o0 + 2L * NT * NHD + row * NHD + k0);
        half8 hv;
#pragma unroll
        for (int jj = 0; jj < 8; jj++) {
            float v = b0 * (float)v0[jj] + b1 * (float)v1[jj] + b2 * (float)v2[jj];
            hv[jj] = (_Float16)v;
            long idx = (long)NT * NOD + (long)(n0 + row) * NHD + k0 + jj;
            if (f) ((float*)outp)[idx] = v;
            else   ((__hip_bfloat16*)outp)[idx] = __float2bfloat16(v);
        }
        *(half8*)&h16[row][k0] = hv;
    }
    __syncthreads();
    int w = t >> 6, lane = t & 63;
    int col = lane & 15, kq = lane >> 4;
    const _Float16* abase = fcw16 + (long)(w * 16 + col) * NHD + kq * 8;
    f32x4 acc = (f32x4){0.f, 0.f, 0.f, 0.f};
    for (int kk = 0; kk < 16; kk++) {
        half8 bfrag = *(const half8*)&h16[col][kq * 8 + kk * 32];
        half8 afrag = *(const half8*)(abase + kk * 32);
        acc = __builtin_amdgcn_mfma_f32_16x16x32_f16(afrag, bfrag, acc, 0, 0, 0);
    }
#pragma unroll
    for (int r = 0; r < 4; r++) {
        int arow = w * 16 + kq * 4 + r;
        float v = acc[r] + fc_b[arow];
        long oidx = (long)(n0 + col) * NOD + arow;
        if (f) ((float*)outp)[oidx] = v;
        else   ((__hip_bfloat16*)outp)[oidx] = __float2bfloat16(v);
    }
}

extern "C" void kernel_launch(void* const* d_in, const int* in_sizes, int n_in,
                              void* d_out, int out_size, void* d_ws, size_t ws_size,
                              hipStream_t stream) {
    const int* indices = (const int*)d_in[1];
    const int* dst     = (const int*)d_in[2];

    float* ws  = (float*)d_ws;
    int*   wsi = (int*)d_ws;

    bool big = ws_size >= NEED_WORDS * 4UL;

    const int betaacc = big ? BETAACC_N : BETAACC_F;
    const int beta    = big ? BETA_N    : BETA_F;
    const int counts  = big ? COUNTS_N  : COUNTS_F;
    const int offs    = big ? OFFS_N    : OFFS_F;
    const int cursor  = big ? CURSOR_N  : CURSOR_F;
    const int attnf   = big ? ATTNF_N   : ATTNF_F;
    const int fc1w    = big ? FC1W_N    : FC1W_F;
    const int fc1b    = big ? FC1B_N    : FC1B_F;
    const int fc2w    = big ? FC2W_N    : FC2W_F;
    const int fcw     = big ? FCW_N     : FCW_F;
    const int fcb     = big ? FCB_N     : FCB_F;
    const int rvec    = big ? RVEC_N    : RVEC_F;
    const int outsw   = big ? OUTS_N    : OUTS_F;
    _Float16* outsp = (_Float16*)(ws + outsw);
    _Float16* fc1h  = (_Float16*)(ws + fc1w);
    _Float16* fcw16 = (_Float16*)(ws + fcw);

    // one merged memset covering betaacc..counts (includes unused gaps; safe)
    if (big)
        hipMemsetAsync((char*)d_ws + (size_t)BETAACC_N * 4, 0,
                       (size_t)(COUNTS_N + NSEG - BETAACC_N) * 4, stream);
    else
        hipMemsetAsync((char*)d_ws + (size_t)BETAACC_F * 4, 0,
                       (size_t)(COUNTS_F + NSEG - BETAACC_F) * 4, stream);

    // fused: dtype detect + small cvts + finalr + atilde
    k_prep<<<1, 256, 0, stream>>>((const unsigned short*)d_in[0],
                                  d_in[3], d_in[4], d_in[6], d_in[7], d_in[9],
                                  ws, wsi + FLAG_W,
                                  ws + rvec, ws + attnf, ws + fc1b, ws + fc2w,
                                  ws + fcb);

    // fc1_w -> f16 [128][512] and fc_w -> f16 [64][512] in ONE launch
    k_cvt_h4_dual<<<(NAD * NHD / 4 + NOD * NHD / 4 + 255) / 256, 256, 0, stream>>>(
        d_in[5], (half4*)fc1h, NAD * NHD / 4,
        d_in[8], (half4*)fcw16, NOD * NHD / 4, wsi + FLAG_W);
    k_count<<<(NP * NE + 255) / 256, 256, 0, stream>>>(dst, wsi + counts);
    k_scan<<<1, 256, 0, stream>>>(wsi + counts, wsi + offs, wsi + cursor);

    if (big) {
        _Float16* featH = (_Float16*)(ws + FEATH_N);
        // fused feature cvt + scores
        k_score<<<(NN + 127) / 128, 256, 0, stream>>>(d_in[0], wsi + FLAG_W,
                                                      ws + ATILDE_W, ws + SCORE_N, featH);
        // scatter (byte-scaled) + fused per-(edge,head) exp(leaky(score))
        k_scatter2<<<(NP * NE + 255) / 256, 256, 0, stream>>>(dst, indices,
                                                              wsi + cursor,
                                                              (int4*)(wsi + EIDX_N),
                                                              ws + SCORE_N, ws + EH_N);
        k_agg2<<<NSEG, 64, 0, stream>>>(featH, (const int4*)(wsi + EIDX_N),
                                        ws + EH_N, ws + FINALR_W,
                                        wsi + offs, outsp);
    } else {
        k_cvt<<<(NN * IND + 255) / 256, 256, 0, stream>>>(d_in[0], ws + FEATF_F,
                                                          NN * IND, wsi + FLAG_W);
        k_scatter<<<(NP * NE + 255) / 256, 256, 0, stream>>>(dst, wsi + cursor,
                                                             wsi + ELIST_F);
        k_agg<<<NSEG, 64, 0, stream>>>(ws + FEATF_F, indices, ws + attnf, ws,
                                       wsi + offs, wsi + ELIST_F, outsp);
    }

    // MFMA fc1: 1536 node-tiles of 16 rows, 4 waves/block -> 384 blocks
    k_fc1<<<NP * NT / 16 / 4, 256, 0, stream>>>(outsp, fc1h, ws + fc1b, ws + betaacc);
    k_beta<<<1, 128, 0, stream>>>(ws + betaacc, ws + fc2w, ws + beta);
    k_final<<<NT / NB, 256, 0, stream>>>(outsp, ws + beta, fcw16, ws + fcb,
                                         d_out, wsi + FLAG_W);
}

// Round 16
// 307.524 us; speedup vs baseline: 1.0126x; 1.0126x over previous
//
#include <hip/hip_runtime.h>
#include <hip/hip_bf16.h>
#include <hip/hip_fp16.h>

// Problem constants (from reference)
#define NP   3        // metapaths
#define NE   250000   // edges per metapath
#define NL   3        // metapath length
#define NT   8192     // targets
#define NN   100000   // nodes
#define IND  64       // in_dim
#define ND2  32       // in_dim/2 complex pairs
#define NH   8        // heads
#define NAD  128      // attn_vec_dim
#define NOD  64       // out_dim
#define NHD  512      // heads * in_dim
#define LALPHA 0.01f
#define NSEG (NP*NT)
#define NB   16       // nodes per block in k_final

typedef __attribute__((ext_vector_type(8))) _Float16 half8;
typedef __attribute__((ext_vector_type(4))) _Float16 half4;
typedef __attribute__((ext_vector_type(4))) float f32x4;
typedef __attribute__((ext_vector_type(4))) unsigned int uint4v;

// ---------------- NEW-path ws layout (words). NEED = 25872000 words ---------
#define FLAG_W    0
#define FINALR_W  64        // 576
#define ATILDE_W  704       // 4608 : atilde [p][l][h][64] f32 (1/3 folded in)
#define BETAACC_N 5376      // 384
#define BETA_N    5760      // 4
#define COUNTS_N  6144      // 24576
#define OFFS_N    30720     // 24577
#define CURSOR_N  55360     // 24576
#define EIDX_N    80000     // 3000000 (750000 int4; BYTE-scaled node offsets)
#define ATTNF_N   3080000   // 1536
#define FC1W_N    3081600   // slot: fc1_w staged f16 [128][512]
#define FC1B_N    3147136   // 128
#define FC2W_N    3147264   // 128
#define FCW_N     3147392   // slot: fc_w staged f16 [64][512]
#define FCB_N     3180160   // 64
#define RVEC_N    3180224   // 192
#define FEATH_N   3180544   // 3200000 words = 6.4M f16
#define SCORE_N   6380544   // 7200000 : S [NN][72]  (c*8+h within row)
#define OUTS_N    13580544  // 6291456 words = 12.58M f16 : elu(outs) [P][NT][512]
#define EH_N      19872000  // 6000000 f32 : EH[pos][8] = exp(leaky(score))
#define NEED_WORDS 25872000UL   // <= 26163456 proven present since round 4

// ---------------- FALLBACK ws layout (round-3 proven; outs f16) -------------
#define BETAACC_F 1024
#define BETA_F    1472
#define COUNTS_F  2048
#define OFFS_F    26624
#define CURSOR_F  51264
#define ELIST_F   75904
#define FEATF_F   825920
#define ATTNF_F   7225920
#define FC1W_F    7227456
#define FC1B_F    7292992
#define FC2W_F    7293120
#define FCW_F     7293248
#define FCB_F     7326016
#define RVEC_F    7326080
#define OUTS_F    7326272

__device__ __forceinline__ float bf2f(unsigned short u) {
    union { unsigned int i; float f; } c; c.i = ((unsigned int)u) << 16; return c.f;
}

// v_fma_mix_f32: acc = f32(f16 lo/hi of xpair) * s + acc  (cvt fused into fma)
__device__ __forceinline__ void fmamix_lo(float& acc, unsigned int xpair, float s) {
    asm("v_fma_mix_f32 %0, %1, %2, %0 op_sel_hi:[1,0,0]"
        : "+v"(acc) : "v"(xpair), "v"(s));
}
__device__ __forceinline__ void fmamix_hi(float& acc, unsigned int xpair, float s) {
    asm("v_fma_mix_f32 %0, %1, %2, %0 op_sel:[1,0,0] op_sel_hi:[1,0,0]"
        : "+v"(acc) : "v"(xpair), "v"(s));
}

// ---------------- k_prep: detect dtype + small cvts + finalr + atilde -------
__global__ __launch_bounds__(256) void k_prep(
        const unsigned short* __restrict__ feat_raw,
        const void* __restrict__ rvec_src, const void* __restrict__ attn_src,
        const void* __restrict__ fc1b_src, const void* __restrict__ fc2w_src,
        const void* __restrict__ fcb_src,
        float* __restrict__ ws, int* __restrict__ flag,
        float* __restrict__ rvecf, float* __restrict__ attnf,
        float* __restrict__ fc1bf, float* __restrict__ fc2wf,
        float* __restrict__ fcbf) {
    __shared__ int cnt;
    int t = threadIdx.x;
    if (t == 0) cnt = 0;
    __syncthreads();
    int wild = 0;
    for (int i = t; i < 512; i += 256) {
        unsigned short u = feat_raw[i];
        int e = (u >> 7) & 0xFF;
        if (u != 0 && (e < 0x60 || e > 0x90)) wild++;
    }
    for (int off = 32; off; off >>= 1) wild += __shfl_xor(wild, off);
    if ((t & 63) == 0) atomicAdd(&cnt, wild);
    __syncthreads();
    int f = cnt > 64 ? 1 : 0;
    if (t == 0) *flag = f;
    // small converts
    for (int i = t; i < 192; i += 256)
        rvecf[i] = f ? ((const float*)rvec_src)[i] : bf2f(((const unsigned short*)rvec_src)[i]);
    for (int i = t; i < 1536; i += 256)
        attnf[i] = f ? ((const float*)attn_src)[i] : bf2f(((const unsigned short*)attn_src)[i]);
    if (t < 128) fc1bf[t] = f ? ((const float*)fc1b_src)[t] : bf2f(((const unsigned short*)fc1b_src)[t]);
    if (t < 128) fc2wf[t] = f ? ((const float*)fc2w_src)[t] : bf2f(((const unsigned short*)fc2w_src)[t]);
    if (t < 64)  fcbf[t]  = f ? ((const float*)fcb_src)[t]  : bf2f(((const unsigned short*)fcb_src)[t]);
    __syncthreads();
    // finalr
    if (t < NP * ND2) {
        int p = t / ND2, j = t % ND2;
        float re = rvecf[(p * ND2 + j) * 2 + 0];
        float im = rvecf[(p * ND2 + j) * 2 + 1];
        float inv = rsqrtf(re * re + im * im);
        float nre = re * inv, nim = im * inv;
        float f1r = nre, f1i = -nim;              // f[1] = conj(r)
        float f0r = f1r * nre - f1i * nim;        // f[0] = f[1]*r
        float f0i = f1r * nim + f1i * nre;
        float* fr = ws + FINALR_W + p * NL * ND2 * 2;
        fr[(0 * ND2 + j) * 2 + 0] = f0r; fr[(0 * ND2 + j) * 2 + 1] = f0i;
        fr[(1 * ND2 + j) * 2 + 0] = f1r; fr[(1 * ND2 + j) * 2 + 1] = f1i;
        fr[(2 * ND2 + j) * 2 + 0] = 1.f; fr[(2 * ND2 + j) * 2 + 1] = 0.f;
    }
    __syncthreads();
    // atilde[p][l][h][d] = (1/3) * cmul(at[p,h], conj(c_pl))[d]
    const float* finalr = ws + FINALR_W;
    float* atil = ws + ATILDE_W;
    for (int i = t; i < NP * NL * NH * IND; i += 256) {
        int d = i & 63, h = (i >> 6) & 7, l = (i >> 9) % 3, p = i / (64 * 8 * 3);
        int j = d >> 1; bool im = (d & 1) != 0;
        float cr = finalr[(p * NL * ND2 + l * ND2 + j) * 2 + 0];
        float ci = finalr[(p * NL * ND2 + l * ND2 + j) * 2 + 1];
        float ar = attnf[(p * NH + h) * IND + 2 * j];
        float ai = attnf[(p * NH + h) * IND + 2 * j + 1];
        float v = im ? (ai * cr - ar * ci) : (ar * cr + ai * ci);
        atil[i] = v * (1.f / 3.f);
    }
}

// ---------------- generic converts -----------------------------------------
__global__ void k_cvt(const void* __restrict__ src, float* __restrict__ dst, int n,
                      const int* __restrict__ flag) {
    int i = blockIdx.x * blockDim.x + threadIdx.x;
    if (i >= n) return;
    if (*flag) dst[i] = ((const float*)src)[i];
    else       dst[i] = bf2f(((const unsigned short*)src)[i]);
}

__device__ __forceinline__ half4 cvt_one_h4(const void* src, int i, int f) {
    half4 o;
    if (f) {
        float4 v = ((const float4*)src)[i];
        o[0] = (_Float16)v.x; o[1] = (_Float16)v.y; o[2] = (_Float16)v.z; o[3] = (_Float16)v.w;
    } else {
        ushort4 u = ((const ushort4*)src)[i];
        o[0] = (_Float16)bf2f(u.x); o[1] = (_Float16)bf2f(u.y);
        o[2] = (_Float16)bf2f(u.z); o[3] = (_Float16)bf2f(u.w);
    }
    return o;
}

// dual f16 convert: fc1_w then fc_w in a single launch
__global__ void k_cvt_h4_dual(const void* __restrict__ s1, half4* __restrict__ d1, int n1,
                              const void* __restrict__ s2, half4* __restrict__ d2, int n2,
                              const int* __restrict__ flag) {
    int i = blockIdx.x * blockDim.x + threadIdx.x;
    int f = *flag;
    if (i < n1)            d1[i] = cvt_one_h4(s1, i, f);
    else if (i - n1 < n2)  d2[i - n1] = cvt_one_h4(s2, i - n1, f);
}

// ---------------- per-node scores (FUSED feature cvt): reads raw features,
// writes featH f16 AND S[n][c*8+h] (row stride 72) ---------------------------
__global__ __launch_bounds__(256) void k_score(const void* __restrict__ feat_src,
                                               const int* __restrict__ flag,
                                               const float* __restrict__ atil,
                                               float* __restrict__ S,
                                               _Float16* __restrict__ featH) {
    __shared__ float xs[128][68];
    __shared__ float as[72][68];
    int t = threadIdx.x;
    int nbase = blockIdx.x * 128;
    int f = *flag;
    for (int i = t; i < 72 * 64; i += 256) as[i >> 6][i & 63] = atil[i];
    for (int c = t; c < 2048; c += 256) {
        int nloc = c >> 4, cc = c & 15;
        int node = nbase + nloc;
        float4 v;
        if (node < NN) {
            if (f) v = ((const float4*)feat_src)[(size_t)node * 16 + cc];
            else {
                ushort4 u = ((const ushort4*)feat_src)[(size_t)node * 16 + cc];
                v = make_float4(bf2f(u.x), bf2f(u.y), bf2f(u.z), bf2f(u.w));
            }
        } else v = make_float4(0.f, 0.f, 0.f, 0.f);
        int d0 = cc * 4;
        xs[nloc][d0 + 0] = v.x; xs[nloc][d0 + 1] = v.y;
        xs[nloc][d0 + 2] = v.z; xs[nloc][d0 + 3] = v.w;
        if (node < NN) {
            half4 hv;
            hv[0] = (_Float16)v.x; hv[1] = (_Float16)v.y;
            hv[2] = (_Float16)v.z; hv[3] = (_Float16)v.w;
            *(half4*)(featH + (size_t)node * IND + d0) = hv;
        }
    }
    __syncthreads();
    int lane = t & 63, w = t >> 6;
    int g = lane >> 3, h = lane & 7;
    int nloc = (w * 8 + g) * 4;                      // 4 nodes per thread
    float acc[9][4];
#pragma unroll
    for (int c = 0; c < 9; c++)
#pragma unroll
        for (int u = 0; u < 4; u++) acc[c][u] = 0.f;
    for (int ch = 0; ch < 16; ch++) {
        float4 xv[4];
#pragma unroll
        for (int u = 0; u < 4; u++) xv[u] = *(const float4*)&xs[nloc + u][ch * 4];
#pragma unroll
        for (int c = 0; c < 9; c++) {
            float4 av = *(const float4*)&as[c * 8 + h][ch * 4];
#pragma unroll
            for (int u = 0; u < 4; u++)
                acc[c][u] += xv[u].x * av.x + xv[u].y * av.y + xv[u].z * av.z + xv[u].w * av.w;
        }
    }
#pragma unroll
    for (int u = 0; u < 4; u++) {
        int node = nbase + nloc + u;
        if (node < NN) {
#pragma unroll
            for (int c = 0; c < 9; c++)
                S[(long)node * 72 + c * 8 + h] = acc[c][u];
        }
    }
}

// ---------------- CSR build -------------------------------------------------
__global__ void k_count(const int* __restrict__ dst, int* __restrict__ counts) {
    int id = blockIdx.x * blockDim.x + threadIdx.x;
    if (id >= NP * NE) return;
    int p = id / NE;
    atomicAdd(&counts[p * NT + dst[id]], 1);
}

__global__ __launch_bounds__(256) void k_scan(const int* __restrict__ counts,
                                              int* __restrict__ offs,
                                              int* __restrict__ cursor) {
    __shared__ int wtot[4];
    int t = threadIdx.x;
    const int CH = NSEG / 256;  // 96
    int base = t * CH;
    int s = 0;
    for (int i = 0; i < CH; i++) s += counts[base + i];
    int l = t & 63, w = t >> 6;
    int v = s;
    for (int off = 1; off < 64; off <<= 1) {
        int u = __shfl_up(v, off);
        if (l >= off) v += u;
    }
    if (l == 63) wtot[w] = v;
    __syncthreads();
    int wb = 0;
    for (int i = 0; i < w; i++) wb += wtot[i];
    int run = wb + v - s;
    for (int i = 0; i < CH; i++) {
        int c = counts[base + i];
        offs[base + i] = run; cursor[base + i] = run;
        run += c;
    }
    if (t == 255) offs[NSEG] = wb + v;
}

// scatter BYTE-scaled node triples AND compute EH[pos][h]
__global__ void k_scatter2(const int* __restrict__ dst, const int* __restrict__ indices,
                           int* __restrict__ cursor, int4* __restrict__ eidx,
                           const float* __restrict__ S, float* __restrict__ EH) {
    int id = blockIdx.x * blockDim.x + threadIdx.x;
    if (id >= NP * NE) return;
    int p = id / NE, e = id % NE;
    int pos = atomicAdd(&cursor[p * NT + dst[id]], 1);
    const int* ip = indices + (long)p * NE * NL + (long)e * NL;
    int n0 = ip[0], n1 = ip[1], n2 = ip[2];
    eidx[pos] = make_int4(n0 << 7, n1 << 7, n2 << 7, 0);   // bytes into featH
    const float* S0 = S + (long)n0 * 72 + p * 24;
    const float* S1 = S + (long)n1 * 72 + p * 24 + 8;
    const float* S2 = S + (long)n2 * 72 + p * 24 + 16;
    float4 a0 = *(const float4*)S0, b0 = *(const float4*)(S0 + 4);
    float4 a1 = *(const float4*)S1, b1 = *(const float4*)(S1 + 4);
    float4 a2 = *(const float4*)S2, b2 = *(const float4*)(S2 + 4);
    float4 lo, hi;
    {
        float s;
        s = a0.x + a1.x + a2.x; lo.x = __expf(fmaxf(s, LALPHA * s));
        s = a0.y + a1.y + a2.y; lo.y = __expf(fmaxf(s, LALPHA * s));
        s = a0.z + a1.z + a2.z; lo.z = __expf(fmaxf(s, LALPHA * s));
        s = a0.w + a1.w + a2.w; lo.w = __expf(fmaxf(s, LALPHA * s));
        s = b0.x + b1.x + b2.x; hi.x = __expf(fmaxf(s, LALPHA * s));
        s = b0.y + b1.y + b2.y; hi.y = __expf(fmaxf(s, LALPHA * s));
        s = b0.z + b1.z + b2.z; hi.z = __expf(fmaxf(s, LALPHA * s));
        s = b0.w + b1.w + b2.w; hi.w = __expf(fmaxf(s, LALPHA * s));
    }
    float* ehp = EH + (long)pos * 8;
    *(float4*)ehp = lo;
    *(float4*)(ehp + 4) = hi;
}

// fallback: scatter edge id only
__global__ void k_scatter(const int* __restrict__ dst, int* __restrict__ cursor,
                          int* __restrict__ elist) {
    int id = blockIdx.x * blockDim.x + threadIdx.x;
    if (id >= NP * NE) return;
    int p = id / NE, e = id % NE;
    int pos = atomicAdd(&cursor[p * NT + dst[id]], 1);
    elist[pos] = e;
}

// ---------------- edge aggregation: round-14 proven form (saddr + fma_mix) --
// lane = 8*h + q handles (head h, dims d in [8q, 8q+8))
__global__ __launch_bounds__(64) void k_agg2(
        const _Float16* __restrict__ featH, const int4* __restrict__ eidx,
        const float* __restrict__ EH, const float* __restrict__ finalr,
        const int* __restrict__ offs, _Float16* __restrict__ outs) {
    int b = blockIdx.x;
    int p = b / NT;
    int t = threadIdx.x;
    int h = t >> 3, q = t & 7;
    const unsigned fB = (unsigned)(q << 4);   // q*8 elems * 2B
    const char* Fb = (const char*)featH;

    float a0[8], a1[8], a2[8];
#pragma unroll
    for (int r = 0; r < 8; r++) { a0[r] = 0.f; a1[r] = 0.f; a2[r] = 0.f; }
    float se = 0.f;

    int beg = offs[b], end = offs[b + 1];
    const float* EHh = EH + h;   // EH[pos*8 + h]

    int i = beg;
    for (; i + 4 <= end; i += 4) {
        int4 ee[4];
        float ehv[4];
        half8 x0[4], x1[4], x2[4];
#pragma unroll
        for (int u = 0; u < 4; u++) ehv[u] = EHh[(long)(i + u) * 8];
#pragma unroll
        for (int u = 0; u < 4; u++) ee[u] = eidx[i + u];
#pragma unroll
        for (int u = 0; u < 4; u++) {
            x0[u] = *(const half8*)(Fb + (unsigned)((unsigned)ee[u].x + fB));
            x1[u] = *(const half8*)(Fb + (unsigned)((unsigned)ee[u].y + fB));
            x2[u] = *(const half8*)(Fb + (unsigned)((unsigned)ee[u].z + fB));
        }
#pragma unroll
        for (int u = 0; u < 4; u++) {
            float eh = ehv[u];
            se += eh;
            uint4v w0 = __builtin_bit_cast(uint4v, x0[u]);
            uint4v w1 = __builtin_bit_cast(uint4v, x1[u]);
            uint4v w2 = __builtin_bit_cast(uint4v, x2[u]);
#pragma unroll
            for (int jp = 0; jp < 4; jp++) {
                fmamix_lo(a0[2 * jp], w0[jp], eh); fmamix_hi(a0[2 * jp + 1], w0[jp], eh);
                fmamix_lo(a1[2 * jp], w1[jp], eh); fmamix_hi(a1[2 * jp + 1], w1[jp], eh);
                fmamix_lo(a2[2 * jp], w2[jp], eh); fmamix_hi(a2[2 * jp + 1], w2[jp], eh);
            }
        }
    }
    for (; i < end; i++) {
        int4 e = eidx[i];
        float eh = EHh[(long)i * 8];
        se += eh;
        half8 x0 = *(const half8*)(Fb + (unsigned)((unsigned)e.x + fB));
        half8 x1 = *(const half8*)(Fb + (unsigned)((unsigned)e.y + fB));
        half8 x2 = *(const half8*)(Fb + (unsigned)((unsigned)e.z + fB));
#pragma unroll
        for (int r = 0; r < 8; r++) {
            a0[r] += eh * (float)x0[r];
            a1[r] += eh * (float)x1[r];
            a2[r] += eh * (float)x2[r];
        }
    }

    // epilogue: ft = (1/3) * sum_l rot_l(acc_l) / se ; elu ; f16 store
    const float* fr = finalr + p * NL * ND2 * 2;
    float sc = (end > beg) ? (1.f / 3.f) / se : 0.f;
    half8 o;
#pragma unroll
    for (int jj = 0; jj < 4; jj++) {
        int j = 4 * q + jj;
        float c0r = fr[(0 * ND2 + j) * 2 + 0], c0i = fr[(0 * ND2 + j) * 2 + 1];
        float c1r = fr[(1 * ND2 + j) * 2 + 0], c1i = fr[(1 * ND2 + j) * 2 + 1];
        float ar, ai, vr, vi;
        ar = a0[2 * jj]; ai = a0[2 * jj + 1];
        vr = ar * c0r - ai * c0i; vi = ar * c0i + ai * c0r;
        ar = a1[2 * jj]; ai = a1[2 * jj + 1];
        vr += ar * c1r - ai * c1i; vi += ar * c1i + ai * c1r;
        vr += a2[2 * jj]; vi += a2[2 * jj + 1];   // l=2 rotation is identity
        vr *= sc; vi *= sc;
        vr = vr > 0.f ? vr : __expf(vr) - 1.f;
        vi = vi > 0.f ? vi : __expf(vi) - 1.f;
        o[2 * jj]     = (_Float16)vr;
        o[2 * jj + 1] = (_Float16)vi;
    }
    *(half8*)(outs + (long)b * NHD + (h << 6) + (q << 3)) = o;
}

// ---------------- FALLBACK edge aggregation (round-3 proven; f16 store) -----
__global__ __launch_bounds__(64) void k_agg(
        const float* __restrict__ feat, const int* __restrict__ indices,
        const float* __restrict__ attn, const float* __restrict__ ws_f,
        const int* __restrict__ offs, const int* __restrict__ elist,
        _Float16* __restrict__ outs) {
    int b = blockIdx.x;
    int p = b / NT;
    int d = threadIdx.x;
    int j = d >> 1;
    bool isim = (d & 1) != 0;
    const float* fr = ws_f + FINALR_W + p * NL * ND2 * 2;
    float cr[NL], ci[NL];
#pragma unroll
    for (int l = 0; l < NL; l++) {
        cr[l] = fr[(l * ND2 + j) * 2 + 0];
        ci[l] = fr[(l * ND2 + j) * 2 + 1];
    }
    float at[NH];
#pragma unroll
    for (int h = 0; h < NH; h++) at[h] = attn[(p * NH + h) * IND + d];
    float ft[NH], se[NH];
#pragma unroll
    for (int h = 0; h < NH; h++) { ft[h] = 0.f; se[h] = 0.f; }
    int beg = offs[b], end = offs[b + 1];
    const int* idxp = indices + (long)p * NE * NL;
    for (int i = beg; i < end; i++) {
        int e = elist[i];
        int nn[3] = { idxp[e * 3 + 0], idxp[e * 3 + 1], idxp[e * 3 + 2] };
        float hid = 0.f;
#pragma unroll
        for (int l = 0; l < NL; l++) {
            float x = feat[(long)nn[l] * IND + d];
            float xp = __shfl_xor(x, 1);
            float re = isim ? xp : x;
            float im = isim ? x : xp;
            hid += isim ? (re * ci[l] + im * cr[l]) : (re * cr[l] - im * ci[l]);
        }
        hid *= (1.f / 3.f);
#pragma unroll
        for (int h = 0; h < NH; h++) {
            float v = hid * at[h];
#pragma unroll
            for (int off = 32; off; off >>= 1) v += __shfl_xor(v, off);
            float a = v > 0.f ? v : LALPHA * v;
            float eh = __expf(a);
            se[h] += eh;
            ft[h] += eh * hid;
        }
    }
    _Float16* orow = outs + (long)b * NHD;
    bool has = end > beg;
#pragma unroll
    for (int h = 0; h < NH; h++) {
        float v = has ? ft[h] / fmaxf(se[h], 1e-20f) : 0.f;
        v = v > 0.f ? v : (__expf(v) - 1.f);
        orow[h * IND + d] = (_Float16)v;
    }
}

// ---------------- fc1 -> tanh -> sum over nodes, via MFMA (round-9 proven) --
__global__ __launch_bounds__(256) void k_fc1(
        const _Float16* __restrict__ outs, const _Float16* __restrict__ fc1h,
        const float* __restrict__ fc1_b, float* __restrict__ betaacc) {
    __shared__ float red[4][NAD];
    int tid = threadIdx.x;
    int wid = tid >> 6, lane = tid & 63;
    int nt = blockIdx.x * 4 + wid;     // node-tile index (16 outs rows each)
    int p  = blockIdx.x / (NT / 16 / 4);  // 128 blocks per metapath
    int col = lane & 15, kq = lane >> 4;

    const _Float16* brow  = outs + ((long)nt * 16 + col) * NHD + kq * 8;
    const _Float16* abase = fc1h + (long)col * NHD + kq * 8;

    f32x4 acc[8];
#pragma unroll
    for (int ta = 0; ta < 8; ta++) acc[ta] = (f32x4){0.f, 0.f, 0.f, 0.f};

    for (int kk = 0; kk < 16; kk++) {
        half8 b = *(const half8*)(brow + kk * 32);
#pragma unroll
        for (int ta = 0; ta < 8; ta++) {
            half8 a = *(const half8*)(abase + (long)ta * 16 * NHD + kk * 32);
            acc[ta] = __builtin_amdgcn_mfma_f32_16x16x32_f16(a, b, acc[ta], 0, 0, 0);
        }
    }

#pragma unroll
    for (int ta = 0; ta < 8; ta++) {
#pragma unroll
        for (int r = 0; r < 4; r++) {
            int arow = ta * 16 + kq * 4 + r;
            float v = tanhf(acc[ta][r] + fc1_b[arow]);
            v += __shfl_xor(v, 1); v += __shfl_xor(v, 2);
            v += __shfl_xor(v, 4); v += __shfl_xor(v, 8);
            if (col == 0) red[wid][arow] = v;
        }
    }
    __syncthreads();
    if (tid < NAD) {
        float s = red[0][tid] + red[1][tid] + red[2][tid] + red[3][tid];
        atomicAdd(&betaacc[p * NAD + tid], s);
    }
}

__global__ void k_beta(const float* __restrict__ betaacc,
                       const float* __restrict__ fc2_w, float* __restrict__ beta) {
    __shared__ float lds[NP][NAD];
    int t = threadIdx.x;
    for (int p = 0; p < NP; p++)
        lds[p][t] = betaacc[p * NAD + t] * (1.f / NT) * fc2_w[t];
    __syncthreads();
    if (t == 0) {
        float s[NP];
        for (int p = 0; p < NP; p++) {
            s[p] = 0.f;
            for (int a = 0; a < NAD; a++) s[p] += lds[p][a];
        }
        float m = fmaxf(s[0], fmaxf(s[1], s[2]));
        float e0 = expf(s[0] - m), e1 = expf(s[1] - m), e2 = expf(s[2] - m);
        float inv = 1.f / (e0 + e1 + e2);
        beta[0] = e0 * inv; beta[1] = e1 * inv; beta[2] = e2 * inv;
    }
}

// ---------------- h = sum_p beta_p*outs_p ; h_fc via MFMA -------------------
__global__ __launch_bounds__(256) void k_final(
        const _Float16* __restrict__ outs, const float* __restrict__ beta,
        const _Float16* __restrict__ fcw16, const float* __restrict__ fc_b,
        void* __restrict__ outp, const int* __restrict__ flag) {
    __shared__ _Float16 h16[16][520];   // pad 520: uniform bank spread
    int n0 = blockIdx.x * NB;
    int t = threadIdx.x;
    int f = *flag;
    float b0 = beta[0], b1 = beta[1], b2 = beta[2];
    const _Float16* o0 = outs + (long)n0 * NHD;
    for (int c = t; c < NB * NHD / 8; c += 256) {
        int row = c >> 6, k0 = (c & 63) * 8;
        half8 v0 = *(const half8*)(o0 + row * NHD + k0);
        half8 v1 = *(const half8*)(o0 + (long)NT * NHD + row * NHD + k0);
        half8 v2 = *(const half8*)(o0 + 2L * NT * NHD + row * NHD + k0);
        half8 hv;
#pragma unroll
        for (int jj = 0; jj < 8; jj++) {
            float v = b0 * (float)v0[jj] + b1 * (float)v1[jj] + b2 * (float)v2[jj];
            hv[jj] = (_Float16)v;
            long idx = (long)NT * NOD + (long)(n0 + row) * NHD + k0 + jj;
            if (f) ((float*)outp)[idx] = v;
            else   ((__hip_bfloat16*)outp)[idx] = __float2bfloat16(v);
        }
        *(half8*)&h16[row][k0] = hv;
    }
    __syncthreads();
    int w = t >> 6, lane = t & 63;
    int col = lane & 15, kq = lane >> 4;
    const _Float16* abase = fcw16 + (long)(w * 16 + col) * NHD + kq * 8;
    f32x4 acc = (f32x4){0.f, 0.f, 0.f, 0.f};
    for (int kk = 0; kk < 16; kk++) {
        half8 bfrag = *(const half8*)&h16[col][kq * 8 + kk * 32];
        half8 afrag = *(const half8*)(abase + kk * 32);
        acc = __builtin_amdgcn_mfma_f32_16x16x32_f16(afrag, bfrag, acc, 0, 0, 0);
    }
#pragma unroll
    for (int r = 0; r < 4; r++) {
        int arow = w * 16 + kq * 4 + r;
        float v = acc[r] + fc_b[arow];
        long oidx = (long)(n0 + col) * NOD + arow;
        if (f) ((float*)outp)[oidx] = v;
        else   ((__hip_bfloat16*)outp)[oidx] = __float2bfloat16(v);
    }
}

extern "C" void kernel_launch(void* const* d_in, const int* in_sizes, int n_in,
                              void* d_out, int out_size, void* d_ws, size_t ws_size,
                              hipStream_t stream) {
    const int* indices = (const int*)d_in[1];
    const int* dst     = (const int*)d_in[2];

    float* ws  = (float*)d_ws;
    int*   wsi = (int*)d_ws;

    bool big = ws_size >= NEED_WORDS * 4UL;

    const int betaacc = big ? BETAACC_N : BETAACC_F;
    const int beta    = big ? BETA_N    : BETA_F;
    const int counts  = big ? COUNTS_N  : COUNTS_F;
    const int offs    = big ? OFFS_N    : OFFS_F;
    const int cursor  = big ? CURSOR_N  : CURSOR_F;
    const int attnf   = big ? ATTNF_N   : ATTNF_F;
    const int fc1w    = big ? FC1W_N    : FC1W_F;
    const int fc1b    = big ? FC1B_N    : FC1B_F;
    const int fc2w    = big ? FC2W_N    : FC2W_F;
    const int fcw     = big ? FCW_N     : FCW_F;
    const int fcb     = big ? FCB_N     : FCB_F;
    const int rvec    = big ? RVEC_N    : RVEC_F;
    const int outsw   = big ? OUTS_N    : OUTS_F;
    _Float16* outsp = (_Float16*)(ws + outsw);
    _Float16* fc1h  = (_Float16*)(ws + fc1w);
    _Float16* fcw16 = (_Float16*)(ws + fcw);

    // one merged memset covering betaacc..counts (includes unused gaps; safe)
    if (big)
        hipMemsetAsync((char*)d_ws + (size_t)BETAACC_N * 4, 0,
                       (size_t)(COUNTS_N + NSEG - BETAACC_N) * 4, stream);
    else
        hipMemsetAsync((char*)d_ws + (size_t)BETAACC_F * 4, 0,
                       (size_t)(COUNTS_F + NSEG - BETAACC_F) * 4, stream);

    // fused: dtype detect + small cvts + finalr + atilde
    k_prep<<<1, 256, 0, stream>>>((const unsigned short*)d_in[0],
                                  d_in[3], d_in[4], d_in[6], d_in[7], d_in[9],
                                  ws, wsi + FLAG_W,
                                  ws + rvec, ws + attnf, ws + fc1b, ws + fc2w,
                                  ws + fcb);

    // fc1_w -> f16 [128][512] and fc_w -> f16 [64][512] in ONE launch
    k_cvt_h4_dual<<<(NAD * NHD / 4 + NOD * NHD / 4 + 255) / 256, 256, 0, stream>>>(
        d_in[5], (half4*)fc1h, NAD * NHD / 4,
        d_in[8], (half4*)fcw16, NOD * NHD / 4, wsi + FLAG_W);
    k_count<<<(NP * NE + 255) / 256, 256, 0, stream>>>(dst, wsi + counts);
    k_scan<<<1, 256, 0, stream>>>(wsi + counts, wsi + offs, wsi + cursor);

    if (big) {
        _Float16* featH = (_Float16*)(ws + FEATH_N);
        // fused feature cvt + scores
        k_score<<<(NN + 127) / 128, 256, 0, stream>>>(d_in[0], wsi + FLAG_W,
                                                      ws + ATILDE_W, ws + SCORE_N, featH);
        // scatter (byte-scaled) + fused per-(edge,head) exp(leaky(score))
        k_scatter2<<<(NP * NE + 255) / 256, 256, 0, stream>>>(dst, indices,
                                                              wsi + cursor,
                                                              (int4*)(wsi + EIDX_N),
                                                              ws + SCORE_N, ws + EH_N);
        k_agg2<<<NSEG, 64, 0, stream>>>(featH, (const int4*)(wsi + EIDX_N),
                                        ws + EH_N, ws + FINALR_W,
                                        wsi + offs, outsp);
    } else {
        k_cvt<<<(NN * IND + 255) / 256, 256, 0, stream>>>(d_in[0], ws + FEATF_F,
                                                          NN * IND, wsi + FLAG_W);
        k_scatter<<<(NP * NE + 255) / 256, 256, 0, stream>>>(dst, wsi + cursor,
                                                             wsi + ELIST_F);
        k_agg<<<NSEG, 64, 0, stream>>>(ws + FEATF_F, indices, ws + attnf, ws,
                                       wsi + offs, wsi + ELIST_F, outsp);
    }

    // MFMA fc1: 1536 node-tiles of 16 rows, 4 waves/block -> 384 blocks
    k_fc1<<<NP * NT / 16 / 4, 256, 0, stream>>>(outsp, fc1h, ws + fc1b, ws + betaacc);
    k_beta<<<1, 128, 0, stream>>>(ws + betaacc, ws + fc2w, ws + beta);
    k_final<<<NT / NB, 256, 0, stream>>>(outsp, ws + beta, fcw16, ws + fcb,
                                         d_out, wsi + FLAG_W);
}